// Round 8
// baseline (224.733 us; speedup 1.0000x reference)
//
#include <hip/hip_runtime.h>
#include <hip/hip_bf16.h>
#include <math.h>

typedef __hip_bfloat16 bf16;
typedef short bf16x8 __attribute__((ext_vector_type(8)));
typedef float f32x4 __attribute__((ext_vector_type(4)));

#define R_TOT 4096   // B*N
#define NJ 31

// ---- workspace layout (float element offsets) ----
#define OFF_AE   0
#define OFF_QK   1048576   // qk: 4096*10 floats
#define OFF_S1   2097152
#define OFF_SE   3145728
#define OFF_HW   4415488
#define OFF_ENT  4542464
#define OFF_X    4546560
#define OFF_W    5595136   // canonical weights base
// relative to W:
#define W_E1W   0
#define W_E1B   640
#define W_E2P   768        // e2 B-pack: 32768 bf16
#define W_E2B   33536
#define W_H1W   33792
#define W_H1B   101120
#define W_H2WT  101376     // (unused legacy h2 B-pack slot)
#define W_H2B   166912
#define W_HEW   167168
#define W_HEB   167680
#define W_W1EP  167684     // W1e B-pack: 8192 bf16 (4096 floats)
#define W_HE2P  171780     // E = he@hm2 B-pack: 4096 bf16 (2048 floats)
#define W_CB    173828     // cb0, cb1 (2 floats)
#define W_S1P   200452     // s1 B-pack: 65536 bf16
#define W_KW    233220
#define W_VW    235780
#define W_VB    238340
#define W_DECWT 238596     // dec B-pack: 262144 bf16
#define W_DECB  500740
#define W_QKM   501252     // M = qw^T@kw B-pack: 4096 bf16
#define OFF_FLAG 6100992   // int flag

// ---- output element offsets ----
#define OUT0 0
#define OUT1 2097152
#define OUT2 2224128
#define OUT3 2351104
#define OUT4 2351105
#define OUT5 2478081

__device__ __forceinline__ float b2f(bf16 x) { return __bfloat162float(x); }
__device__ __forceinline__ float ldin(const void* p, int i, int flag) {
    return flag ? b2f(((const bf16*)p)[i]) : ((const float*)p)[i];
}
__device__ __forceinline__ void stout(void* p, int i, float v, int flag) {
    if (flag) ((bf16*)p)[i] = __float2bfloat16(v);
    else      ((float*)p)[i] = v;
}
__device__ __forceinline__ unsigned short f2bbits(float v) {
    bf16 h = __float2bfloat16(v);
    return *(unsigned short*)&h;
}

// ---------------- K0: dtype detector ----------------
__global__ void k_detect(const void* emb, int* flagp) {
    int ln = threadIdx.x;
    float x = ((const float*)emb)[ln];
    int sane = (x == x) && (fabsf(x) < 1e20f);
    unsigned long long m = __ballot(sane);
    if (ln == 0) flagp[0] = (__popcll(m) == 64) ? 0 : 1;  // 0=fp32, 1=bf16
}

// ---------------- K0b: convert weights: fp32 canon + MFMA B-packs ----------------
__global__ __launch_bounds__(256) void k_conv(
        const void* e1w, const void* e1b, const void* e2w, const void* e2b,
        const void* h1w, const void* h1b, const void* h2w, const void* h2b,
        const void* hew, const void* heb, const void* qw,  const void* kw,
        const void* vw,  const void* vb,  const void* decw,const void* decb,
        float* W, const int* flagp) {
    int flag = flagp[0];
    int idx = blockIdx.x * 256 + threadIdx.x;
    if (idx < 262144) {
        // dec B-pack: idx = ((kt*32+nt)*64+lane)*8+jj ; B[k][n] = dec_w[n*512+k]
        int jj   = idx & 7;
        int lane = (idx >> 3) & 63;
        int tile = idx >> 9;          // 0..511
        int nt = tile & 31, kt = tile >> 5;
        int n = nt * 16 + (lane & 15);
        int k = kt * 32 + ((lane >> 4) << 3) + jj;
        ((unsigned short*)(W + W_DECWT))[idx] = f2bbits(ldin(decw, n * 512 + k, flag));
    }
    int j = idx - 262144;
    if (j >= 0 && j < 98304) {  // MFMA B-packs for e2 / s1
        int p;
        const void* src; int ldm, Wdst;
        if (j < 32768)      { p = j;          src = e2w; ldm = 128; Wdst = W_E2P; }
        else                { p = j - 32768;  src = h1w; ldm = 263; Wdst = W_S1P; }
        int jj   = p & 7;
        int lane = (p >> 3) & 63;
        int tile = p >> 9;
        int nt = tile & 15, kt = tile >> 4;
        int n = nt * 16 + (lane & 15);
        int k = kt * 32 + ((lane >> 4) << 3) + jj;
        ((unsigned short*)(W + Wdst))[p] = f2bbits(ldin(src, n * ldm + k, flag));
    } else if (j >= 98304 && j < 174082) {   // fp32 canon for the rest
        int q2 = j - 98304;
        if      (q2 < 640)   W[W_E1W  + q2]           = ldin(e1w,  q2,          flag);
        else if (q2 < 768)   W[W_E1B  + (q2 - 640)]   = ldin(e1b,  q2 - 640,    flag);
        else if (q2 < 1024)  W[W_E2B  + (q2 - 768)]   = ldin(e2b,  q2 - 768,    flag);
        else if (q2 < 68352) W[W_H1W  + (q2 - 1024)]  = ldin(h1w,  q2 - 1024,   flag);
        else if (q2 < 68608) W[W_H1B  + (q2 - 68352)] = ldin(h1b,  q2 - 68352,  flag);
        else if (q2 < 68864) W[W_H2B  + (q2 - 68608)] = ldin(h2b,  q2 - 68608,  flag);
        else if (q2 < 69376) W[W_HEW  + (q2 - 68864)] = ldin(hew,  q2 - 68864,  flag);
        else if (q2 < 69378) W[W_HEB  + (q2 - 69376)] = ldin(heb,  q2 - 69376,  flag);
        else if (q2 < 71938) W[W_KW   + (q2 - 69378)] = ldin(kw,   q2 - 69378,  flag);
        else if (q2 < 74498) W[W_VW   + (q2 - 71938)] = ldin(vw,   q2 - 71938,  flag);
        else if (q2 < 74754) W[W_VB   + (q2 - 74498)] = ldin(vb,   q2 - 74498,  flag);
        else                 W[W_DECB + (q2 - 74754)] = ldin(decb, q2 - 74754,  flag);
    }
}

// ---------------- K0c: M = qw^T @ kw (256x10), packed as MFMA B-fragments ----------------
__global__ __launch_bounds__(256) void k_qkm(const void* qw, const void* kw, float* W, const int* flagp) {
    int flag = flagp[0];
    int p = blockIdx.x * 256 + threadIdx.x;   // 16 blocks -> 4096 entries
    if (p >= 4096) return;
    int jj = p & 7, lane = (p >> 3) & 63, kt = p >> 9;
    int k = kt * 32 + ((lane >> 4) << 3) + jj;   // c index 0..255
    int n = lane & 15;                           // t index (10 real)
    float v = 0.f;
    if (n < 10) {
        for (int d = 0; d < 256; d++)
            v += ldin(qw, d * 256 + k, flag) * ldin(kw, d * 10 + n, flag);
    }
    ((unsigned short*)(W + W_QKM))[p] = f2bbits(v);
}

// ---------------- K0d: W1e B-pack, E = he@hm2 B-pack, cb consts ----------------
__global__ __launch_bounds__(256) void k_hel(const void* h1w, const void* h2w, const void* h2b,
                                             const void* hew, const void* heb,
                                             float* W, const int* flagp) {
    int flag = flagp[0];
    int p = blockIdx.x * 256 + threadIdx.x;   // 49 blocks -> 12290 entries
    if (p < 8192) {
        // W1e pack: single K-tile (K=32, t<7 real): p = (nt*64+lane)*8+jj
        int jj = p & 7, lane = (p >> 3) & 63, nt = p >> 9;   // nt 0..15
        int n = nt * 16 + (lane & 15);           // c
        int k = ((lane >> 4) << 3) + jj;         // t
        float v = (k < 7) ? ldin(h1w, n * 263 + 256 + k, flag) : 0.f;
        ((unsigned short*)(W + W_W1EP))[p] = f2bbits(v);
    } else if (p < 12288) {
        // E pack: E[i][c] = sum_d hew[i,d]*h2w[d,c]; N=16 (2 real), K=256
        int q = p - 8192;
        int jj = q & 7, lane = (q >> 3) & 63, kt = q >> 9;   // kt 0..7
        int n = lane & 15;                       // i
        int c = kt * 32 + ((lane >> 4) << 3) + jj;
        float v = 0.f;
        if (n < 2) {
            for (int d = 0; d < 256; d++)
                v += ldin(hew, n * 256 + d, flag) * ldin(h2w, d * 256 + c, flag);
        }
        ((unsigned short*)(W + W_HE2P))[q] = f2bbits(v);
    } else if (p < 12290) {
        int i = p - 12288;
        float v = ldin(heb, i, flag);
        for (int d = 0; d < 256; d++)
            v += ldin(hew, i * 256 + d, flag) * ldin(h2b, d, flag);
        W[W_CB + i] = v;
    }
}

// ---------------- K1: embed MLP + s1 + qk, all via MFMA ----------------
__global__ __launch_bounds__(256) void k_embed(const void* emb, const float* W, const int* flagp,
                                               float* aews, float* qkws, float* s1ws) {
    int flag = flagp[0];
    int r0 = blockIdx.x * 32;   // 128 blocks
    __shared__ float embL[32][12];
    __shared__ unsigned short hB[32][136];
    __shared__ unsigned short aeB[32][264];
    int tid = threadIdx.x;
    for (int idx = tid; idx < 32 * 11; idx += 256) {
        int s = idx / 11, t = idx % 11;
        embL[s][t] = ldin(emb, (r0 + s) * 11 + t, flag);
    }
    __syncthreads();
    for (int idx = tid; idx < 32 * 128; idx += 256) {
        int s = idx >> 7, jo = idx & 127;
        float v = W[W_E1B + jo];
#pragma unroll
        for (int t = 0; t < 5; t++) v += W[W_E1W + jo * 5 + t] * embL[s][4 + t];
        hB[s][jo] = f2bbits(v > 0.f ? v : 0.01f * v);
    }
    __syncthreads();
    int wv = tid >> 6, ln = tid & 63;
    int lr = ln & 15, quad = ln >> 4;
    {
        const bf16x8* Bp = (const bf16x8*)(W + W_E2P);
        f32x4 acc[2][4];
#pragma unroll
        for (int mt = 0; mt < 2; mt++)
#pragma unroll
            for (int nt = 0; nt < 4; nt++) acc[mt][nt] = (f32x4){0.f, 0.f, 0.f, 0.f};
#pragma unroll
        for (int kt = 0; kt < 4; kt++) {
            bf16x8 af[2];
#pragma unroll
            for (int mt = 0; mt < 2; mt++)
                af[mt] = *(const bf16x8*)&hB[mt * 16 + lr][kt * 32 + (quad << 3)];
#pragma unroll
            for (int nt = 0; nt < 4; nt++) {
                bf16x8 bfr = Bp[(kt * 16 + (wv * 4 + nt)) * 64 + ln];
#pragma unroll
                for (int mt = 0; mt < 2; mt++)
                    acc[mt][nt] = __builtin_amdgcn_mfma_f32_16x16x32_bf16(af[mt], bfr, acc[mt][nt], 0, 0, 0);
            }
        }
#pragma unroll
        for (int nt = 0; nt < 4; nt++) {
            int d = wv * 64 + nt * 16 + lr;
            float bias = W[W_E2B + d];
#pragma unroll
            for (int mt = 0; mt < 2; mt++)
#pragma unroll
                for (int reg = 0; reg < 4; reg++) {
                    int m = mt * 16 + quad * 4 + reg;
                    float v = acc[mt][nt][reg] + bias;
                    v = v > 0.f ? v : 0.01f * v;
                    aeB[m][d] = f2bbits(v);
                    aews[(r0 + m) * 256 + d] = v;
                }
        }
    }
    __syncthreads();
    {
        const bf16x8* Bs = (const bf16x8*)(W + W_S1P);
        f32x4 sac[2][4];
#pragma unroll
        for (int mt = 0; mt < 2; mt++)
#pragma unroll
            for (int nt = 0; nt < 4; nt++) sac[mt][nt] = (f32x4){0.f, 0.f, 0.f, 0.f};
#pragma unroll
        for (int kt = 0; kt < 8; kt++) {
            bf16x8 af[2];
#pragma unroll
            for (int mt = 0; mt < 2; mt++)
                af[mt] = *(const bf16x8*)&aeB[mt * 16 + lr][kt * 32 + (quad << 3)];
#pragma unroll
            for (int nt = 0; nt < 4; nt++) {
                bf16x8 bs = Bs[(kt * 16 + (wv * 4 + nt)) * 64 + ln];
#pragma unroll
                for (int mt = 0; mt < 2; mt++)
                    sac[mt][nt] = __builtin_amdgcn_mfma_f32_16x16x32_bf16(af[mt], bs, sac[mt][nt], 0, 0, 0);
            }
        }
#pragma unroll
        for (int nt = 0; nt < 4; nt++) {
            int d = wv * 64 + nt * 16 + lr;
            float bias = W[W_H1B + d];
#pragma unroll
            for (int mt = 0; mt < 2; mt++)
#pragma unroll
                for (int reg = 0; reg < 4; reg++) {
                    int m = mt * 16 + quad * 4 + reg;
                    s1ws[(r0 + m) * 256 + d] = sac[mt][nt][reg] + bias;
                }
        }
        // qk = ae @ M (256x16, 10 real cols); waves 0,1 each take one m-tile
        if (wv < 2) {
            const bf16x8* Bm = (const bf16x8*)(W + W_QKM);
            f32x4 qk = (f32x4){0.f, 0.f, 0.f, 0.f};
#pragma unroll
            for (int kt = 0; kt < 8; kt++) {
                bf16x8 af = *(const bf16x8*)&aeB[wv * 16 + lr][kt * 32 + (quad << 3)];
                qk = __builtin_amdgcn_mfma_f32_16x16x32_bf16(af, Bm[kt * 64 + ln], qk, 0, 0, 0);
            }
            if (lr < 10) {
#pragma unroll
                for (int reg = 0; reg < 4; reg++) {
                    int m = wv * 16 + quad * 4 + reg;
                    qkws[(r0 + m) * 10 + lr] = qk[reg];
                }
            }
        }
    }
}

// ---------------- K2: edge features (7) + goal polar (3) ----------------
__global__ void k_edges(const void* emb, const int* flagp, float* sews, void* out) {
    int flag = flagp[0];
    int idx = blockIdx.x * 256 + threadIdx.x;
    if (idx >= R_TOT * NJ) return;
    int r = idx / NJ, jp = idx - r * NJ;
    int b = r >> 5, i = r & 31;
    int j = jp + (jp >= i ? 1 : 0);
    int ei = r * 11, ej = (b * 32 + j) * 11;
    float pix = ldin(emb, ei + 0, flag), piy = ldin(emb, ei + 1, flag);
    float hix = ldin(emb, ei + 2, flag), hiy = ldin(emb, ei + 3, flag);
    float pjx = ldin(emb, ej + 0, flag), pjy = ldin(emb, ej + 1, flag);
    float hjx = ldin(emb, ej + 2, flag), hjy = ldin(emb, ej + 3, flag);
    float ajx = ldin(emb, ej + 7, flag), ajy = ldin(emb, ej + 8, flag);
    float gjx = ldin(emb, ej + 9, flag), gjy = ldin(emb, ej + 10, flag);
    float dx = pjx - pix, dy = pjy - piy;
    float dist = sqrtf(dx * dx + dy * dy);
    float hai = atan2f(hiy, hix);
    float ang = atan2f(dy, dx) - hai;
    float gx = gjx - pix, gy = gjy - piy;
    float gdist = sqrtf(gx * gx + gy * gy);
    float gang = atan2f(gy, gx) - hai;
    float* o = sews + idx * 10;
    o[0] = dist * (1.f / 12.f);
    o[1] = cosf(ang); o[2] = sinf(ang);
    o[3] = hjx; o[4] = hjy; o[5] = ajx; o[6] = ajy;
    o[7] = gdist; o[8] = cosf(gang); o[9] = sinf(gang);
    stout(out, OUT2 + idx, dist, flag);
}

// ---------------- K3: hard logits via E-fold (2 small MFMA stages) + gumbel ----------------
__global__ __launch_bounds__(256) void k_hard(const float* s1ws, const float* sews, const float* W,
                                              const void* gum, const int* flagp,
                                              float* hwws, void* out) {
    int flag = flagp[0];
    int r = blockIdx.x;
    __shared__ unsigned short eA[32][40];    // edge A-frags (K=32, t<7 real)
    __shared__ unsigned short a1[32][264];   // relu(s1 + edge@W1e^T), bf16
    __shared__ float pj[4][32][2];           // per-wave partial logits
    int tid = threadIdx.x;
    for (int idx = tid; idx < 32 * 32; idx += 256) {
        int m = idx >> 5, k = idx & 31;
        float v = 0.f;
        if (m < NJ && k < 7) v = sews[(r * NJ + m) * 10 + k];
        eA[m][k] = f2bbits(v);
    }
    __syncthreads();
    int wv = tid >> 6, ln = tid & 63;
    int lr = ln & 15, quad = ln >> 4;
    // phase A: a1 = relu(s1 + edge @ W1e^T); s1 folded in as C-init (per-column)
    {
        const bf16x8* Bp = (const bf16x8*)(W + W_W1EP);
        bf16x8 af0 = *(const bf16x8*)&eA[lr][quad << 3];
        bf16x8 af1 = *(const bf16x8*)&eA[16 + lr][quad << 3];
#pragma unroll
        for (int nt = 0; nt < 4; nt++) {
            int gnt = wv * 4 + nt;
            int d = gnt * 16 + lr;
            float s1v = s1ws[r * 256 + d];
            f32x4 acc0 = (f32x4){s1v, s1v, s1v, s1v};
            f32x4 acc1 = acc0;
            bf16x8 b = Bp[gnt * 64 + ln];
            acc0 = __builtin_amdgcn_mfma_f32_16x16x32_bf16(af0, b, acc0, 0, 0, 0);
            acc1 = __builtin_amdgcn_mfma_f32_16x16x32_bf16(af1, b, acc1, 0, 0, 0);
#pragma unroll
            for (int reg = 0; reg < 4; reg++) {
                a1[(quad << 2) + reg][d]      = f2bbits(fmaxf(acc0[reg], 0.f));
                a1[16 + (quad << 2) + reg][d] = f2bbits(fmaxf(acc1[reg], 0.f));
            }
        }
    }
    __syncthreads();
    // phase B: logits = a1 @ E^T ; wave wv covers kt {2wv, 2wv+1}
    {
        const bf16x8* Ep = (const bf16x8*)(W + W_HE2P);
        f32x4 l0 = (f32x4){0.f, 0.f, 0.f, 0.f};
        f32x4 l1 = (f32x4){0.f, 0.f, 0.f, 0.f};
#pragma unroll
        for (int kk = 0; kk < 2; kk++) {
            int kt = wv * 2 + kk;
            bf16x8 a0 = *(const bf16x8*)&a1[lr][kt * 32 + (quad << 3)];
            bf16x8 a1f = *(const bf16x8*)&a1[16 + lr][kt * 32 + (quad << 3)];
            bf16x8 b = Ep[kt * 64 + ln];
            l0 = __builtin_amdgcn_mfma_f32_16x16x32_bf16(a0, b, l0, 0, 0, 0);
            l1 = __builtin_amdgcn_mfma_f32_16x16x32_bf16(a1f, b, l1, 0, 0, 0);
        }
        if (lr < 2) {
#pragma unroll
            for (int reg = 0; reg < 4; reg++) {
                pj[wv][(quad << 2) + reg][lr]      = l0[reg];
                pj[wv][16 + (quad << 2) + reg][lr] = l1[reg];
            }
        }
    }
    __syncthreads();
    if (tid < NJ) {
        int j = tid;
        float p0 = pj[0][j][0] + pj[1][j][0] + pj[2][j][0] + pj[3][j][0];
        float p1 = pj[0][j][1] + pj[1][j][1] + pj[2][j][1] + pj[3][j][1];
        float l0 = p0 + W[W_CB + 0], l1 = p1 + W[W_CB + 1];
        float u0 = ldin(gum, (r * NJ + j) * 2 + 0, flag);
        float u1 = ldin(gum, (r * NJ + j) * 2 + 1, flag);
        float g0 = -logf(-logf(u0 + 1e-10f) + 1e-10f);
        float g1 = -logf(-logf(u1 + 1e-10f) + 1e-10f);
        float dl = ((l1 + g1) - (l0 + g0)) * 2.0f;  // / tau (=0.5)
        float hwv = 1.f / (1.f + expf(-dl));
        stout(out, OUT1 + r * NJ + j, l1, flag);
        stout(out, OUT4 + r * NJ + j, hwv, flag);
        hwws[r * NJ + j] = hwv;
    }
}

// ---------------- K4: attention via qk-fold + softmax + V+x + entropy ----------------
__global__ __launch_bounds__(256) void k_attn(const float* qkws, const float* sews, const float* hwws,
                                              const float* W, const int* flagp,
                                              float* xws, float* entws, void* out) {
    int flag = flagp[0];
    int r = blockIdx.x;
    __shared__ float seL[NJ][10];
    __shared__ float cL[32];
    __shared__ float qkL[10];
    int tid = threadIdx.x;
    for (int idx = tid; idx < NJ * 10; idx += 256) ((float*)seL)[idx] = sews[r * NJ * 10 + idx];
    if (tid < 10) qkL[tid] = qkws[r * 10 + tid];
    __syncthreads();
    int wv = tid >> 6, ln = tid & 63;
    if (wv == 0) {
        float sc = -1e30f;
        if (ln < NJ) {
            float p = 0.f;
#pragma unroll
            for (int t = 0; t < 10; t++) p += qkL[t] * seL[ln][t];
            sc = p * (1.f / 16.f);
        }
        float m = sc;
#pragma unroll
        for (int s = 32; s >= 1; s >>= 1) m = fmaxf(m, __shfl_xor(m, s, 64));
        float e = (ln < NJ) ? expf(sc - m) : 0.f;
        float sum = e;
#pragma unroll
        for (int s = 32; s >= 1; s >>= 1) sum += __shfl_xor(sum, s, 64);
        float sw = e / sum;
        float hv = (ln < NJ) ? hwws[r * NJ + ln] : 0.f;
        float cmb = sw * hv;
        if (ln < NJ) {
            cL[ln] = cmb;
            stout(out, OUT5 + r * NJ + ln, cmb, flag);
        }
        float csum = cmb;
#pragma unroll
        for (int s = 32; s >= 1; s >>= 1) csum += __shfl_xor(csum, s, 64);
        float cwn = cmb / (csum + 1e-6f);
        float et = (ln < NJ) ? -cwn * logf(cwn + 1e-6f) : 0.f;
#pragma unroll
        for (int s = 32; s >= 1; s >>= 1) et += __shfl_xor(et, s, 64);
        if (ln == 0) entws[r] = et;
    }
    __syncthreads();
    float vwr[10];
#pragma unroll
    for (int t = 0; t < 10; t++) vwr[t] = W[W_VW + tid * 10 + t];
    float vbv = W[W_VB + tid];
    float x = 0.f;
    for (int j = 0; j < NJ; j++) {
        float v = vbv;
#pragma unroll
        for (int t = 0; t < 10; t++) v += vwr[t] * seL[j][t];
        v = fmaxf(v, 0.f);
        x += v * cL[j];
    }
    xws[r * 256 + tid] = x;
}

// ---------------- K5: decoder via MFMA ----------------
__global__ __launch_bounds__(256) void k_dec(const float* aews, const float* xws, const float* W,
                                             const int* flagp, void* out) {
    int flag = flagp[0];
    int r0 = (blockIdx.x >> 2) * 32;
    int nq = blockIdx.x & 3;
    __shared__ unsigned short finB[32][520];
    int tid = threadIdx.x;
    for (int idx = tid; idx < 32 * 512; idx += 256) {
        int s = idx >> 9, c = idx & 511;
        float v = (c < 256) ? aews[(r0 + s) * 256 + c] : xws[(r0 + s) * 256 + (c - 256)];
        finB[s][c] = f2bbits(v);
    }
    __syncthreads();
    int wv = tid >> 6, ln = tid & 63;
    int lr = ln & 15, quad = ln >> 4;
    const bf16x8* Bp = (const bf16x8*)(W + W_DECWT);
    f32x4 acc[2][2];
#pragma unroll
    for (int mt = 0; mt < 2; mt++)
#pragma unroll
        for (int nt = 0; nt < 2; nt++) acc[mt][nt] = (f32x4){0.f, 0.f, 0.f, 0.f};
#pragma unroll
    for (int kt = 0; kt < 16; kt++) {
        bf16x8 af[2];
#pragma unroll
        for (int mt = 0; mt < 2; mt++)
            af[mt] = *(const bf16x8*)&finB[mt * 16 + lr][kt * 32 + (quad << 3)];
#pragma unroll
        for (int nt = 0; nt < 2; nt++) {
            int gnt = nq * 8 + wv * 2 + nt;
            bf16x8 bfr = Bp[(kt * 32 + gnt) * 64 + ln];
#pragma unroll
            for (int mt = 0; mt < 2; mt++)
                acc[mt][nt] = __builtin_amdgcn_mfma_f32_16x16x32_bf16(af[mt], bfr, acc[mt][nt], 0, 0, 0);
        }
    }
#pragma unroll
    for (int nt = 0; nt < 2; nt++) {
        int d = (nq * 8 + wv * 2 + nt) * 16 + lr;
        float bias = W[W_DECB + d];
#pragma unroll
        for (int mt = 0; mt < 2; mt++)
#pragma unroll
            for (int reg = 0; reg < 4; reg++) {
                int m = mt * 16 + quad * 4 + reg;
                stout(out, OUT0 + (r0 + m) * 512 + d, acc[mt][nt][reg] + bias, flag);
            }
    }
}

// ---------------- K6: entropy mean ----------------
__global__ void k_ent(const float* entws, const int* flagp, void* out) {
    __shared__ float red[4];
    int tid = threadIdx.x;
    float s = 0.f;
    for (int i = tid; i < R_TOT; i += 256) s += entws[i];
#pragma unroll
    for (int m = 32; m >= 1; m >>= 1) s += __shfl_xor(s, m, 64);
    if ((tid & 63) == 0) red[tid >> 6] = s;
    __syncthreads();
    if (tid == 0) {
        float t = red[0] + red[1] + red[2] + red[3];
        stout(out, OUT3, t / (float)R_TOT, flagp[0]);
    }
}

// ---------------- launch ----------------
extern "C" void kernel_launch(void* const* d_in, const int* in_sizes, int n_in,
                              void* d_out, int out_size, void* d_ws, size_t ws_size,
                              hipStream_t stream) {
    const void* emb  = d_in[0];
    const void* gum  = d_in[1];
    const void* e1w  = d_in[2];
    const void* e1b  = d_in[3];
    const void* e2w  = d_in[4];
    const void* e2b  = d_in[5];
    const void* h1w  = d_in[6];
    const void* h1b  = d_in[7];
    const void* h2w  = d_in[8];
    const void* h2b  = d_in[9];
    const void* hew  = d_in[10];
    const void* heb  = d_in[11];
    const void* qw   = d_in[12];
    const void* kw   = d_in[13];
    const void* vw   = d_in[14];
    const void* vb   = d_in[15];
    const void* decw = d_in[16];
    const void* decb = d_in[17];

    float* wsf = (float*)d_ws;
    float* aews = wsf + OFF_AE;
    float* qkws = wsf + OFF_QK;
    float* s1ws = wsf + OFF_S1;
    float* sews = wsf + OFF_SE;
    float* hwws = wsf + OFF_HW;
    float* entw = wsf + OFF_ENT;
    float* xws  = wsf + OFF_X;
    float* W    = wsf + OFF_W;
    int* flagp  = (int*)(wsf + OFF_FLAG);

    hipLaunchKernelGGL(k_detect, dim3(1), dim3(64), 0, stream, emb, flagp);
    hipLaunchKernelGGL(k_conv, dim3(2048), dim3(256), 0, stream,
                       e1w, e1b, e2w, e2b, h1w, h1b, h2w, h2b, hew, heb,
                       qw, kw, vw, vb, decw, decb, W, flagp);
    hipLaunchKernelGGL(k_qkm, dim3(16), dim3(256), 0, stream, qw, kw, W, flagp);
    hipLaunchKernelGGL(k_hel, dim3(49), dim3(256), 0, stream, h1w, h2w, h2b, hew, heb, W, flagp);
    hipLaunchKernelGGL(k_embed, dim3(128), dim3(256), 0, stream, emb, W, flagp, aews, qkws, s1ws);
    hipLaunchKernelGGL(k_edges, dim3(496), dim3(256), 0, stream, emb, flagp, sews, d_out);
    hipLaunchKernelGGL(k_hard, dim3(4096), dim3(256), 0, stream,
                       s1ws, sews, W, gum, flagp, hwws, d_out);
    hipLaunchKernelGGL(k_attn, dim3(4096), dim3(256), 0, stream,
                       qkws, sews, hwws, W, flagp, xws, entw, d_out);
    hipLaunchKernelGGL(k_dec, dim3(512), dim3(256), 0, stream, aews, xws, W, flagp, d_out);
    hipLaunchKernelGGL(k_ent, dim3(1), dim3(256), 0, stream, entw, flagp, d_out);
}

// Round 9
// 185.950 us; speedup vs baseline: 1.2086x; 1.2086x over previous
//
#include <hip/hip_runtime.h>
#include <hip/hip_bf16.h>
#include <math.h>

typedef __hip_bfloat16 bf16;
typedef short bf16x8 __attribute__((ext_vector_type(8)));
typedef float f32x4 __attribute__((ext_vector_type(4)));
typedef unsigned short u16;

#define R_TOT 4096   // B*N
#define NJ 31

// ---- workspace layout (float element offsets) ----
#define OFF_AE   0          // ae as bf16 u16 (4096*256)
#define OFF_QK   1048576    // qk: 4096*10 floats
#define OFF_S1   2097152    // s1: 4096*256 floats
#define OFF_ENT  4542464    // 4096 floats
#define OFF_X    4546560    // x as bf16 u16 (4096*256)
#define OFF_W    5595136    // canonical weights base
// relative to W:
#define W_E1W   0
#define W_E1B   640
#define W_E2P   768        // e2 B-pack: 32768 bf16
#define W_E2B   33536
#define W_H1W   33792
#define W_H1B   101120
#define W_H2B   166912
#define W_HEW   167168
#define W_HEB   167680
#define W_W1EP  167684     // W1e B-pack: 8192 bf16
#define W_HE2P  171780     // E = he@hm2 B-pack: 4096 bf16
#define W_CB    173828     // cb0, cb1
#define W_S1P   200452     // s1 B-pack: 65536 bf16
#define W_KW    233220
#define W_VW    235780
#define W_VB    238340
#define W_DECWT 238596     // dec B-pack: 262144 bf16
#define W_DECB  500740
#define W_QKM   501252     // M = qw^T@kw B-pack: 4096 bf16

// ---- output element offsets ----
#define OUT0 0
#define OUT1 2097152
#define OUT2 2224128
#define OUT3 2351104
#define OUT4 2351105
#define OUT5 2478081

__device__ __forceinline__ float b2f(bf16 x) { return __bfloat162float(x); }
__device__ __forceinline__ float ldin(const void* p, int i, int flag) {
    return flag ? b2f(((const bf16*)p)[i]) : ((const float*)p)[i];
}
__device__ __forceinline__ void stout(void* p, int i, float v, int flag) {
    if (flag) ((bf16*)p)[i] = __float2bfloat16(v);
    else      ((float*)p)[i] = v;
}
__device__ __forceinline__ u16 f2bbits(float v) {
    bf16 h = __float2bfloat16(v);
    return *(u16*)&h;
}
// per-wave inline dtype detect: P(misclassify) = 0.4^64 ~ 0
__device__ __forceinline__ int detect_flag(const void* emb) {
    float x = ((const float*)emb)[threadIdx.x & 63];
    int sane = (x == x) && (fabsf(x) < 1e20f);
    unsigned long long m = __ballot(sane);
    return (__popcll(m) == 64) ? 0 : 1;  // 0=fp32, 1=bf16
}

// ---------------- K0: all weight prep (canon + every MFMA pack + folds) ----------------
__global__ __launch_bounds__(256) void k_prep(
        const void* emb,
        const void* e1w, const void* e1b, const void* e2w, const void* e2b,
        const void* h1w, const void* h1b, const void* h2w, const void* h2b,
        const void* hew, const void* heb, const void* qw,  const void* kw,
        const void* vw,  const void* vb,  const void* decw,const void* decb,
        float* W) {
    int flag = detect_flag(emb);
    int blk = blockIdx.x;
    if (blk < 2048) {
        int idx = blk * 256 + threadIdx.x;
        if (idx < 262144) {
            // dec B-pack: idx = ((kt*32+nt)*64+lane)*8+jj ; B[k][n] = dec_w[n*512+k]
            int jj   = idx & 7;
            int lane = (idx >> 3) & 63;
            int tile = idx >> 9;          // 0..511
            int nt = tile & 31, kt = tile >> 5;
            int n = nt * 16 + (lane & 15);
            int k = kt * 32 + ((lane >> 4) << 3) + jj;
            ((u16*)(W + W_DECWT))[idx] = f2bbits(ldin(decw, n * 512 + k, flag));
        }
        int j = idx - 262144;
        if (j >= 0 && j < 98304) {  // MFMA B-packs for e2 / s1
            int p;
            const void* src; int ldm, Wdst;
            if (j < 32768)      { p = j;          src = e2w; ldm = 128; Wdst = W_E2P; }
            else                { p = j - 32768;  src = h1w; ldm = 263; Wdst = W_S1P; }
            int jj   = p & 7;
            int lane = (p >> 3) & 63;
            int tile = p >> 9;
            int nt = tile & 15, kt = tile >> 4;
            int n = nt * 16 + (lane & 15);
            int k = kt * 32 + ((lane >> 4) << 3) + jj;
            ((u16*)(W + Wdst))[p] = f2bbits(ldin(src, n * ldm + k, flag));
        } else if (j >= 98304 && j < 174082) {   // fp32 canon for the rest
            int q2 = j - 98304;
            if      (q2 < 640)   W[W_E1W  + q2]           = ldin(e1w,  q2,          flag);
            else if (q2 < 768)   W[W_E1B  + (q2 - 640)]   = ldin(e1b,  q2 - 640,    flag);
            else if (q2 < 1024)  W[W_E2B  + (q2 - 768)]   = ldin(e2b,  q2 - 768,    flag);
            else if (q2 < 68352) W[W_H1W  + (q2 - 1024)]  = ldin(h1w,  q2 - 1024,   flag);
            else if (q2 < 68608) W[W_H1B  + (q2 - 68352)] = ldin(h1b,  q2 - 68352,  flag);
            else if (q2 < 68864) W[W_H2B  + (q2 - 68608)] = ldin(h2b,  q2 - 68608,  flag);
            else if (q2 < 69376) W[W_HEW  + (q2 - 68864)] = ldin(hew,  q2 - 68864,  flag);
            else if (q2 < 69378) W[W_HEB  + (q2 - 69376)] = ldin(heb,  q2 - 69376,  flag);
            else if (q2 < 71938) W[W_KW   + (q2 - 69378)] = ldin(kw,   q2 - 69378,  flag);
            else if (q2 < 74498) W[W_VW   + (q2 - 71938)] = ldin(vw,   q2 - 71938,  flag);
            else if (q2 < 74754) W[W_VB   + (q2 - 74498)] = ldin(vb,   q2 - 74498,  flag);
            else                 W[W_DECB + (q2 - 74754)] = ldin(decb, q2 - 74754,  flag);
        }
    } else if (blk < 2064) {
        // qkm: M = qw^T @ kw (256x10) as B-fragments
        int p = (blk - 2048) * 256 + threadIdx.x;   // < 4096
        int jj = p & 7, lane = (p >> 3) & 63, kt = p >> 9;
        int k = kt * 32 + ((lane >> 4) << 3) + jj;
        int n = lane & 15;
        float v = 0.f;
        if (n < 10) {
            for (int d = 0; d < 256; d++)
                v += ldin(qw, d * 256 + k, flag) * ldin(kw, d * 10 + n, flag);
        }
        ((u16*)(W + W_QKM))[p] = f2bbits(v);
    } else {
        // hel: W1e pack, E = he@hm2 pack, cb consts
        int p = (blk - 2064) * 256 + threadIdx.x;   // < 12290 (49 blocks)
        if (p < 8192) {
            int jj = p & 7, lane = (p >> 3) & 63, nt = p >> 9;
            int n = nt * 16 + (lane & 15);
            int k = ((lane >> 4) << 3) + jj;
            float v = (k < 7) ? ldin(h1w, n * 263 + 256 + k, flag) : 0.f;
            ((u16*)(W + W_W1EP))[p] = f2bbits(v);
        } else if (p < 12288) {
            int q = p - 8192;
            int jj = q & 7, lane = (q >> 3) & 63, kt = q >> 9;
            int n = lane & 15;
            int c = kt * 32 + ((lane >> 4) << 3) + jj;
            float v = 0.f;
            if (n < 2) {
                for (int d = 0; d < 256; d++)
                    v += ldin(hew, n * 256 + d, flag) * ldin(h2w, d * 256 + c, flag);
            }
            ((u16*)(W + W_HE2P))[q] = f2bbits(v);
        } else if (p < 12290) {
            int i = p - 12288;
            float v = ldin(heb, i, flag);
            for (int d = 0; d < 256; d++)
                v += ldin(hew, i * 256 + d, flag) * ldin(h2b, d, flag);
            W[W_CB + i] = v;
        }
    }
}

// ---------------- K1: embed MLP + s1 + qk via MFMA (256 blocks x 16 rows) ----------------
__global__ __launch_bounds__(256) void k_embed(const void* emb, const float* W,
                                               u16* aeb, float* qkws, float* s1ws) {
    int flag = detect_flag(emb);
    int r0 = blockIdx.x * 16;
    __shared__ float embL[16][12];
    __shared__ u16 hB[16][136];
    __shared__ u16 aeB[16][264];
    int tid = threadIdx.x;
    for (int idx = tid; idx < 16 * 11; idx += 256) {
        int s = idx / 11, t = idx % 11;
        embL[s][t] = ldin(emb, (r0 + s) * 11 + t, flag);
    }
    __syncthreads();
    for (int idx = tid; idx < 16 * 128; idx += 256) {
        int s = idx >> 7, jo = idx & 127;
        float v = W[W_E1B + jo];
#pragma unroll
        for (int t = 0; t < 5; t++) v += W[W_E1W + jo * 5 + t] * embL[s][4 + t];
        hB[s][jo] = f2bbits(v > 0.f ? v : 0.01f * v);
    }
    __syncthreads();
    int wv = tid >> 6, ln = tid & 63;
    int lr = ln & 15, quad = ln >> 4;
    // ae = leaky(h @ e2w.T + b): M=16, N=256, K=128
    {
        const bf16x8* Bp = (const bf16x8*)(W + W_E2P);
        f32x4 acc[4];
#pragma unroll
        for (int nt = 0; nt < 4; nt++) acc[nt] = (f32x4){0.f, 0.f, 0.f, 0.f};
#pragma unroll
        for (int kt = 0; kt < 4; kt++) {
            bf16x8 af = *(const bf16x8*)&hB[lr][kt * 32 + (quad << 3)];
#pragma unroll
            for (int nt = 0; nt < 4; nt++) {
                bf16x8 bfr = Bp[(kt * 16 + (wv * 4 + nt)) * 64 + ln];
                acc[nt] = __builtin_amdgcn_mfma_f32_16x16x32_bf16(af, bfr, acc[nt], 0, 0, 0);
            }
        }
#pragma unroll
        for (int nt = 0; nt < 4; nt++) {
            int d = wv * 64 + nt * 16 + lr;
            float bias = W[W_E2B + d];
#pragma unroll
            for (int reg = 0; reg < 4; reg++) {
                int m = quad * 4 + reg;
                float v = acc[nt][reg] + bias;
                v = v > 0.f ? v : 0.01f * v;
                u16 bits = f2bbits(v);
                aeB[m][d] = bits;
                aeb[(r0 + m) * 256 + d] = bits;
            }
        }
    }
    __syncthreads();
    // s1 = ae @ h1w[:,:256].T + h1b ; qk = ae @ M  (M=16, K=256)
    {
        const bf16x8* Bs = (const bf16x8*)(W + W_S1P);
        f32x4 sac[4];
#pragma unroll
        for (int nt = 0; nt < 4; nt++) sac[nt] = (f32x4){0.f, 0.f, 0.f, 0.f};
#pragma unroll
        for (int kt = 0; kt < 8; kt++) {
            bf16x8 af = *(const bf16x8*)&aeB[lr][kt * 32 + (quad << 3)];
#pragma unroll
            for (int nt = 0; nt < 4; nt++) {
                bf16x8 bs = Bs[(kt * 16 + (wv * 4 + nt)) * 64 + ln];
                sac[nt] = __builtin_amdgcn_mfma_f32_16x16x32_bf16(af, bs, sac[nt], 0, 0, 0);
            }
        }
#pragma unroll
        for (int nt = 0; nt < 4; nt++) {
            int d = wv * 64 + nt * 16 + lr;
            float bias = W[W_H1B + d];
#pragma unroll
            for (int reg = 0; reg < 4; reg++) {
                int m = quad * 4 + reg;
                s1ws[(r0 + m) * 256 + d] = sac[nt][reg] + bias;
            }
        }
        if (wv == 0) {
            const bf16x8* Bm = (const bf16x8*)(W + W_QKM);
            f32x4 qk = (f32x4){0.f, 0.f, 0.f, 0.f};
#pragma unroll
            for (int kt = 0; kt < 8; kt++) {
                bf16x8 af = *(const bf16x8*)&aeB[lr][kt * 32 + (quad << 3)];
                qk = __builtin_amdgcn_mfma_f32_16x16x32_bf16(af, Bm[kt * 64 + ln], qk, 0, 0, 0);
            }
            if (lr < 10) {
#pragma unroll
                for (int reg = 0; reg < 4; reg++) {
                    int m = quad * 4 + reg;
                    qkws[(r0 + m) * 10 + lr] = qk[reg];
                }
            }
        }
    }
}

// ---------------- K2: fused edges + hard MLP + gumbel + attention + entropy ----------------
__global__ __launch_bounds__(256) void k_fused(const void* emb, const void* gum,
                                               const float* s1ws, const float* qkws, const float* W,
                                               u16* xb, float* entws, void* out) {
    int flag = detect_flag(emb);
    int r = blockIdx.x;
    int b = r >> 5, i = r & 31;
    __shared__ float embB[32][12];
    __shared__ float seL[32][10];
    __shared__ u16 eA[32][32];
    __shared__ u16 a1[32][264];
    __shared__ float pj[4][32][2];
    __shared__ float cL[32];
    __shared__ float qkL[10];
    int tid = threadIdx.x;
    // stage -1: load agent rows of this batch, zero eA, fetch qk
    for (int idx = tid; idx < 32 * 11; idx += 256) {
        int s = idx / 11, t = idx % 11;
        embB[s][t] = ldin(emb, (b * 32 + s) * 11 + t, flag);
    }
    for (int idx = tid; idx < 32 * 32; idx += 256) ((u16*)eA)[idx] = 0;
    if (tid >= 64 && tid < 74) qkL[tid - 64] = qkws[r * 10 + (tid - 64)];
    __syncthreads();
    // stage 0: edge features for 31 neighbors (one thread each)
    if (tid < NJ) {
        int jp = tid;
        int j = jp + (jp >= i ? 1 : 0);
        float pix = embB[i][0], piy = embB[i][1], hix = embB[i][2], hiy = embB[i][3];
        float pjx = embB[j][0], pjy = embB[j][1], hjx = embB[j][2], hjy = embB[j][3];
        float ajx = embB[j][7], ajy = embB[j][8];
        float gjx = embB[j][9], gjy = embB[j][10];
        float dx = pjx - pix, dy = pjy - piy;
        float dist = sqrtf(dx * dx + dy * dy);
        float hai = atan2f(hiy, hix);
        float ang = atan2f(dy, dx) - hai;
        float gx = gjx - pix, gy = gjy - piy;
        float gdist = sqrtf(gx * gx + gy * gy);
        float gang = atan2f(gy, gx) - hai;
        float f[10];
        f[0] = dist * (1.f / 12.f);
        f[1] = cosf(ang); f[2] = sinf(ang);
        f[3] = hjx; f[4] = hjy; f[5] = ajx; f[6] = ajy;
        f[7] = gdist; f[8] = cosf(gang); f[9] = sinf(gang);
#pragma unroll
        for (int t = 0; t < 10; t++) seL[jp][t] = f[t];
#pragma unroll
        for (int t = 0; t < 7; t++) eA[jp][t] = f2bbits(f[t]);
        stout(out, OUT2 + r * NJ + jp, dist, flag);
    }
    __syncthreads();
    int wv = tid >> 6, ln = tid & 63;
    int lr = ln & 15, quad = ln >> 4;
    // stage A: a1 = relu(s1 + edge @ W1e^T), s1 folded as C-init
    {
        const bf16x8* Bp = (const bf16x8*)(W + W_W1EP);
        bf16x8 af0 = *(const bf16x8*)&eA[lr][quad << 3];
        bf16x8 af1 = *(const bf16x8*)&eA[16 + lr][quad << 3];
#pragma unroll
        for (int nt = 0; nt < 4; nt++) {
            int gnt = wv * 4 + nt;
            int d = gnt * 16 + lr;
            float s1v = s1ws[r * 256 + d];
            f32x4 acc0 = (f32x4){s1v, s1v, s1v, s1v};
            f32x4 acc1 = acc0;
            bf16x8 bb = Bp[gnt * 64 + ln];
            acc0 = __builtin_amdgcn_mfma_f32_16x16x32_bf16(af0, bb, acc0, 0, 0, 0);
            acc1 = __builtin_amdgcn_mfma_f32_16x16x32_bf16(af1, bb, acc1, 0, 0, 0);
#pragma unroll
            for (int reg = 0; reg < 4; reg++) {
                a1[(quad << 2) + reg][d]      = f2bbits(fmaxf(acc0[reg], 0.f));
                a1[16 + (quad << 2) + reg][d] = f2bbits(fmaxf(acc1[reg], 0.f));
            }
        }
    }
    __syncthreads();
    // stage B: partial logits = a1 @ E^T
    {
        const bf16x8* Ep = (const bf16x8*)(W + W_HE2P);
        f32x4 l0 = (f32x4){0.f, 0.f, 0.f, 0.f};
        f32x4 l1 = (f32x4){0.f, 0.f, 0.f, 0.f};
#pragma unroll
        for (int kk = 0; kk < 2; kk++) {
            int kt = wv * 2 + kk;
            bf16x8 a0 = *(const bf16x8*)&a1[lr][kt * 32 + (quad << 3)];
            bf16x8 a1f = *(const bf16x8*)&a1[16 + lr][kt * 32 + (quad << 3)];
            bf16x8 bb = Ep[kt * 64 + ln];
            l0 = __builtin_amdgcn_mfma_f32_16x16x32_bf16(a0, bb, l0, 0, 0, 0);
            l1 = __builtin_amdgcn_mfma_f32_16x16x32_bf16(a1f, bb, l1, 0, 0, 0);
        }
        if (lr < 2) {
#pragma unroll
            for (int reg = 0; reg < 4; reg++) {
                pj[wv][(quad << 2) + reg][lr]      = l0[reg];
                pj[wv][16 + (quad << 2) + reg][lr] = l1[reg];
            }
        }
    }
    __syncthreads();
    // stage C (wave 0): gumbel + softmax + combined + entropy
    if (wv == 0) {
        float hwv = 0.f;
        if (ln < NJ) {
            float p0 = pj[0][ln][0] + pj[1][ln][0] + pj[2][ln][0] + pj[3][ln][0];
            float p1 = pj[0][ln][1] + pj[1][ln][1] + pj[2][ln][1] + pj[3][ln][1];
            float l0 = p0 + W[W_CB + 0], l1 = p1 + W[W_CB + 1];
            float u0 = ldin(gum, (r * NJ + ln) * 2 + 0, flag);
            float u1 = ldin(gum, (r * NJ + ln) * 2 + 1, flag);
            float g0 = -logf(-logf(u0 + 1e-10f) + 1e-10f);
            float g1 = -logf(-logf(u1 + 1e-10f) + 1e-10f);
            float dl = ((l1 + g1) - (l0 + g0)) * 2.0f;  // / tau (=0.5)
            hwv = 1.f / (1.f + expf(-dl));
            stout(out, OUT1 + r * NJ + ln, l1, flag);
            stout(out, OUT4 + r * NJ + ln, hwv, flag);
        }
        float sc = -1e30f;
        if (ln < NJ) {
            float p = 0.f;
#pragma unroll
            for (int t = 0; t < 10; t++) p += qkL[t] * seL[ln][t];
            sc = p * (1.f / 16.f);
        }
        float m = sc;
#pragma unroll
        for (int s = 32; s >= 1; s >>= 1) m = fmaxf(m, __shfl_xor(m, s, 64));
        float e = (ln < NJ) ? expf(sc - m) : 0.f;
        float sum = e;
#pragma unroll
        for (int s = 32; s >= 1; s >>= 1) sum += __shfl_xor(sum, s, 64);
        float sw = e / sum;
        float cmb = sw * hwv;
        if (ln < NJ) {
            cL[ln] = cmb;
            stout(out, OUT5 + r * NJ + ln, cmb, flag);
        }
        float csum = cmb;
#pragma unroll
        for (int s = 32; s >= 1; s >>= 1) csum += __shfl_xor(csum, s, 64);
        float cwn = cmb / (csum + 1e-6f);
        float et = (ln < NJ) ? -cwn * logf(cwn + 1e-6f) : 0.f;
#pragma unroll
        for (int s = 32; s >= 1; s >>= 1) et += __shfl_xor(et, s, 64);
        if (ln == 0) entws[r] = et;
    }
    __syncthreads();
    // stage D: x = sum_j relu(v_j) * combined_j
    float vwr[10];
#pragma unroll
    for (int t = 0; t < 10; t++) vwr[t] = W[W_VW + tid * 10 + t];
    float vbv = W[W_VB + tid];
    float x = 0.f;
    for (int j = 0; j < NJ; j++) {
        float v = vbv;
#pragma unroll
        for (int t = 0; t < 10; t++) v += vwr[t] * seL[j][t];
        v = fmaxf(v, 0.f);
        x += v * cL[j];
    }
    xb[r * 256 + tid] = f2bbits(x);
}

// ---------------- K3: decoder via MFMA ----------------
__global__ __launch_bounds__(256) void k_dec(const void* emb, const u16* aeb, const u16* xb,
                                             const float* W, void* out) {
    int flag = detect_flag(emb);
    int r0 = (blockIdx.x >> 2) * 32;
    int nq = blockIdx.x & 3;
    __shared__ u16 finB[32][520];
    int tid = threadIdx.x;
    for (int idx = tid; idx < 32 * 512; idx += 256) {
        int s = idx >> 9, c = idx & 511;
        finB[s][c] = (c < 256) ? aeb[(r0 + s) * 256 + c] : xb[(r0 + s) * 256 + (c - 256)];
    }
    __syncthreads();
    int wv = tid >> 6, ln = tid & 63;
    int lr = ln & 15, quad = ln >> 4;
    const bf16x8* Bp = (const bf16x8*)(W + W_DECWT);
    f32x4 acc[2][2];
#pragma unroll
    for (int mt = 0; mt < 2; mt++)
#pragma unroll
        for (int nt = 0; nt < 2; nt++) acc[mt][nt] = (f32x4){0.f, 0.f, 0.f, 0.f};
#pragma unroll
    for (int kt = 0; kt < 16; kt++) {
        bf16x8 af[2];
#pragma unroll
        for (int mt = 0; mt < 2; mt++)
            af[mt] = *(const bf16x8*)&finB[mt * 16 + lr][kt * 32 + (quad << 3)];
#pragma unroll
        for (int nt = 0; nt < 2; nt++) {
            int gnt = nq * 8 + wv * 2 + nt;
            bf16x8 bfr = Bp[(kt * 32 + gnt) * 64 + ln];
#pragma unroll
            for (int mt = 0; mt < 2; mt++)
                acc[mt][nt] = __builtin_amdgcn_mfma_f32_16x16x32_bf16(af[mt], bfr, acc[mt][nt], 0, 0, 0);
        }
    }
#pragma unroll
    for (int nt = 0; nt < 2; nt++) {
        int d = (nq * 8 + wv * 2 + nt) * 16 + lr;
        float bias = W[W_DECB + d];
#pragma unroll
        for (int mt = 0; mt < 2; mt++)
#pragma unroll
            for (int reg = 0; reg < 4; reg++) {
                int m = mt * 16 + quad * 4 + reg;
                stout(out, OUT0 + (r0 + m) * 512 + d, acc[mt][nt][reg] + bias, flag);
            }
    }
}

// ---------------- K4: entropy mean ----------------
__global__ void k_ent(const void* emb, const float* entws, void* out) {
    int flag = detect_flag(emb);
    __shared__ float red[4];
    int tid = threadIdx.x;
    float s = 0.f;
    for (int i = tid; i < R_TOT; i += 256) s += entws[i];
#pragma unroll
    for (int m = 32; m >= 1; m >>= 1) s += __shfl_xor(s, m, 64);
    if ((tid & 63) == 0) red[tid >> 6] = s;
    __syncthreads();
    if (tid == 0) {
        float t = red[0] + red[1] + red[2] + red[3];
        stout(out, OUT3, t / (float)R_TOT, flag);
    }
}

// ---------------- launch ----------------
extern "C" void kernel_launch(void* const* d_in, const int* in_sizes, int n_in,
                              void* d_out, int out_size, void* d_ws, size_t ws_size,
                              hipStream_t stream) {
    const void* emb  = d_in[0];
    const void* gum  = d_in[1];
    const void* e1w  = d_in[2];
    const void* e1b  = d_in[3];
    const void* e2w  = d_in[4];
    const void* e2b  = d_in[5];
    const void* h1w  = d_in[6];
    const void* h1b  = d_in[7];
    const void* h2w  = d_in[8];
    const void* h2b  = d_in[9];
    const void* hew  = d_in[10];
    const void* heb  = d_in[11];
    const void* qw   = d_in[12];
    const void* kw   = d_in[13];
    const void* vw   = d_in[14];
    const void* vb   = d_in[15];
    const void* decw = d_in[16];
    const void* decb = d_in[17];

    float* wsf = (float*)d_ws;
    u16*   aeb  = (u16*)(wsf + OFF_AE);
    float* qkws = wsf + OFF_QK;
    float* s1ws = wsf + OFF_S1;
    float* entw = wsf + OFF_ENT;
    u16*   xb   = (u16*)(wsf + OFF_X);
    float* W    = wsf + OFF_W;

    hipLaunchKernelGGL(k_prep, dim3(2113), dim3(256), 0, stream,
                       emb, e1w, e1b, e2w, e2b, h1w, h1b, h2w, h2b, hew, heb,
                       qw, kw, vw, vb, decw, decb, W);
    hipLaunchKernelGGL(k_embed, dim3(256), dim3(256), 0, stream, emb, W, aeb, qkws, s1ws);
    hipLaunchKernelGGL(k_fused, dim3(4096), dim3(256), 0, stream,
                       emb, gum, s1ws, qkws, W, xb, entw, d_out);
    hipLaunchKernelGGL(k_dec, dim3(512), dim3(256), 0, stream, emb, aeb, xb, W, d_out);
    hipLaunchKernelGGL(k_ent, dim3(1), dim3(256), 0, stream, emb, entw, d_out);
}

// Round 10
// 161.137 us; speedup vs baseline: 1.3947x; 1.1540x over previous
//
#include <hip/hip_runtime.h>
#include <hip/hip_bf16.h>
#include <math.h>

typedef __hip_bfloat16 bf16;
typedef short bf16x8 __attribute__((ext_vector_type(8)));
typedef float f32x4 __attribute__((ext_vector_type(4)));
typedef unsigned short u16;

#define R_TOT 4096   // B*N
#define NJ 31

// ---- workspace layout (float element offsets) ----
#define OFF_AE   0          // ae as bf16 u16 (4096*256)
#define OFF_QK   1048576    // qk: 4096*10 floats
#define OFF_S1   2097152    // s1: 4096*256 floats
#define OFF_ENT  4542464    // 4096 floats
#define OFF_X    4546560    // x as bf16 u16 (4096*256)
#define OFF_W    5595136    // canonical weights base
// relative to W:
#define W_E1W   0
#define W_E1B   640
#define W_E2P   768        // e2 B-pack: 32768 bf16
#define W_E2B   33536
#define W_H1B   101120
#define W_W1EP  167684     // W1e B-pack: 8192 bf16
#define W_HE2P  171780     // E = he@hm2 B-pack: 4096 bf16
#define W_CB    173828     // cb0, cb1
#define W_S1P   200452     // s1 B-pack: 65536 bf16
#define W_VW    235780
#define W_VB    238340
#define W_DECWT 238596     // dec B-pack: 262144 bf16
#define W_DECB  500740
#define W_QKM   501252     // M = qw^T@kw B-pack: 4096 bf16

// ---- output element offsets ----
#define OUT0 0
#define OUT1 2097152
#define OUT2 2224128
#define OUT3 2351104
#define OUT4 2351105
#define OUT5 2478081

__device__ __forceinline__ float b2f(bf16 x) { return __bfloat162float(x); }
__device__ __forceinline__ float ldin(const void* p, int i, int flag) {
    return flag ? b2f(((const bf16*)p)[i]) : ((const float*)p)[i];
}
__device__ __forceinline__ void stout(void* p, int i, float v, int flag) {
    if (flag) ((bf16*)p)[i] = __float2bfloat16(v);
    else      ((float*)p)[i] = v;
}
__device__ __forceinline__ u16 f2bbits(float v) {
    bf16 h = __float2bfloat16(v);
    return *(u16*)&h;
}
// per-wave inline dtype detect: P(misclassify) = 0.4^64 ~ 0
__device__ __forceinline__ int detect_flag(const void* emb) {
    float x = ((const float*)emb)[threadIdx.x & 63];
    int sane = (x == x) && (fabsf(x) < 1e20f);
    unsigned long long m = __ballot(sane);
    return (__popcll(m) == 64) ? 0 : 1;  // 0=fp32, 1=bf16
}

// ---------------- K0: all weight prep (canon + every MFMA pack + folds) ----------------
// blocks 0..2047    : dec pack + e2/s1 packs + fp32 canon (live entries only)
// blocks 2048..2303 : qkm = qw^T@kw pack, 16-lane-parallel reductions
// blocks 2304..2559 : E = he@hm2 pack, 16-lane-parallel reductions
// blocks 2560..2591 : W1e pack
// block  2592       : cb0/cb1 constants
__global__ __launch_bounds__(256) void k_prep(
        const void* emb,
        const void* e1w, const void* e1b, const void* e2w, const void* e2b,
        const void* h1w, const void* h1b, const void* h2w, const void* h2b,
        const void* hew, const void* heb, const void* qw,  const void* kw,
        const void* vw,  const void* vb,  const void* decw,const void* decb,
        float* W) {
    int flag = detect_flag(emb);
    int blk = blockIdx.x;
    int tid = threadIdx.x;
    if (blk < 2048) {
        int idx = blk * 256 + tid;
        if (idx < 262144) {
            // dec B-pack: idx = ((kt*32+nt)*64+lane)*8+jj ; B[k][n] = dec_w[n*512+k]
            int jj   = idx & 7;
            int lane = (idx >> 3) & 63;
            int tile = idx >> 9;          // 0..511
            int nt = tile & 31, kt = tile >> 5;
            int n = nt * 16 + (lane & 15);
            int k = kt * 32 + ((lane >> 4) << 3) + jj;
            ((u16*)(W + W_DECWT))[idx] = f2bbits(ldin(decw, n * 512 + k, flag));
        }
        int j = idx - 262144;
        if (j >= 0 && j < 98304) {  // MFMA B-packs for e2 / s1
            int p;
            const void* src; int ldm, Wdst;
            if (j < 32768)      { p = j;          src = e2w; ldm = 128; Wdst = W_E2P; }
            else                { p = j - 32768;  src = h1w; ldm = 263; Wdst = W_S1P; }
            int jj   = p & 7;
            int lane = (p >> 3) & 63;
            int tile = p >> 9;
            int nt = tile & 15, kt = tile >> 4;
            int n = nt * 16 + (lane & 15);
            int k = kt * 32 + ((lane >> 4) << 3) + jj;
            ((u16*)(W + Wdst))[p] = f2bbits(ldin(src, n * ldm + k, flag));
        } else if (j >= 98304 && j < 102912) {   // fp32 canon (live only)
            int q2 = j - 98304;
            if      (q2 < 640)   W[W_E1W  + q2]           = ldin(e1w,  q2,          flag);
            else if (q2 < 768)   W[W_E1B  + (q2 - 640)]   = ldin(e1b,  q2 - 640,    flag);
            else if (q2 < 1024)  W[W_E2B  + (q2 - 768)]   = ldin(e2b,  q2 - 768,    flag);
            else if (q2 < 1280)  W[W_H1B  + (q2 - 1024)]  = ldin(h1b,  q2 - 1024,   flag);
            else if (q2 < 3840)  W[W_VW   + (q2 - 1280)]  = ldin(vw,   q2 - 1280,   flag);
            else if (q2 < 4096)  W[W_VB   + (q2 - 3840)]  = ldin(vb,   q2 - 3840,   flag);
            else                 W[W_DECB + (q2 - 4096)]  = ldin(decb, q2 - 4096,   flag);
        }
    } else if (blk < 2304) {
        // qkm: M[c][n] = sum_d qw[d*256+c]*kw[d*10+n]; 16 lanes per entry
        int p = (blk - 2048) * 16 + (tid >> 4);
        int l = tid & 15;
        int jj = p & 7, lane = (p >> 3) & 63, kt = p >> 9;
        int k = kt * 32 + ((lane >> 4) << 3) + jj;
        int n = lane & 15;
        float v = 0.f;
        if (n < 10) {
#pragma unroll
            for (int dd = 0; dd < 16; dd++) {
                int d = l + 16 * dd;
                v += ldin(qw, d * 256 + k, flag) * ldin(kw, d * 10 + n, flag);
            }
        }
        v += __shfl_xor(v, 1, 64); v += __shfl_xor(v, 2, 64);
        v += __shfl_xor(v, 4, 64); v += __shfl_xor(v, 8, 64);
        if (l == 0) ((u16*)(W + W_QKM))[p] = f2bbits(v);
    } else if (blk < 2560) {
        // E pack: E[i][c] = sum_d hew[i*256+d]*h2w[d*256+c]; 16 lanes per entry
        int q = (blk - 2304) * 16 + (tid >> 4);
        int l = tid & 15;
        int jj = q & 7, lane = (q >> 3) & 63, kt = q >> 9;
        int n = lane & 15;
        int c = kt * 32 + ((lane >> 4) << 3) + jj;
        float v = 0.f;
        if (n < 2) {
#pragma unroll
            for (int dd = 0; dd < 16; dd++) {
                int d = l + 16 * dd;
                v += ldin(hew, n * 256 + d, flag) * ldin(h2w, d * 256 + c, flag);
            }
        }
        v += __shfl_xor(v, 1, 64); v += __shfl_xor(v, 2, 64);
        v += __shfl_xor(v, 4, 64); v += __shfl_xor(v, 8, 64);
        if (l == 0) ((u16*)(W + W_HE2P))[q] = f2bbits(v);
    } else if (blk < 2592) {
        // W1e pack
        int p = (blk - 2560) * 256 + tid;   // < 8192
        int jj = p & 7, lane = (p >> 3) & 63, nt = p >> 9;
        int n = nt * 16 + (lane & 15);
        int k = ((lane >> 4) << 3) + jj;
        float v = (k < 7) ? ldin(h1w, n * 263 + 256 + k, flag) : 0.f;
        ((u16*)(W + W_W1EP))[p] = f2bbits(v);
    } else {
        // cb constants: cb_i = heb[i] + sum_d hew[i,d]*h2b[d]
        if (tid < 32) {
            int i = tid >> 4, l = tid & 15;
            float v = 0.f;
#pragma unroll
            for (int dd = 0; dd < 16; dd++) {
                int d = l + 16 * dd;
                v += ldin(hew, i * 256 + d, flag) * ldin(h2b, d, flag);
            }
            v += __shfl_xor(v, 1, 64); v += __shfl_xor(v, 2, 64);
            v += __shfl_xor(v, 4, 64); v += __shfl_xor(v, 8, 64);
            if (l == 0) W[W_CB + i] = v + ldin(heb, i, flag);
        }
    }
}

// ---------------- K1: embed MLP + s1 + qk via MFMA (256 blocks x 16 rows) ----------------
__global__ __launch_bounds__(256) void k_embed(const void* emb, const float* W,
                                               u16* aeb, float* qkws, float* s1ws) {
    int flag = detect_flag(emb);
    int r0 = blockIdx.x * 16;
    __shared__ float embL[16][12];
    __shared__ u16 hB[16][136];
    __shared__ u16 aeB[16][264];
    int tid = threadIdx.x;
    for (int idx = tid; idx < 16 * 11; idx += 256) {
        int s = idx / 11, t = idx % 11;
        embL[s][t] = ldin(emb, (r0 + s) * 11 + t, flag);
    }
    __syncthreads();
    for (int idx = tid; idx < 16 * 128; idx += 256) {
        int s = idx >> 7, jo = idx & 127;
        float v = W[W_E1B + jo];
#pragma unroll
        for (int t = 0; t < 5; t++) v += W[W_E1W + jo * 5 + t] * embL[s][4 + t];
        hB[s][jo] = f2bbits(v > 0.f ? v : 0.01f * v);
    }
    __syncthreads();
    int wv = tid >> 6, ln = tid & 63;
    int lr = ln & 15, quad = ln >> 4;
    // ae = leaky(h @ e2w.T + b): M=16, N=256, K=128
    {
        const bf16x8* Bp = (const bf16x8*)(W + W_E2P);
        f32x4 acc[4];
#pragma unroll
        for (int nt = 0; nt < 4; nt++) acc[nt] = (f32x4){0.f, 0.f, 0.f, 0.f};
#pragma unroll
        for (int kt = 0; kt < 4; kt++) {
            bf16x8 af = *(const bf16x8*)&hB[lr][kt * 32 + (quad << 3)];
#pragma unroll
            for (int nt = 0; nt < 4; nt++) {
                bf16x8 bfr = Bp[(kt * 16 + (wv * 4 + nt)) * 64 + ln];
                acc[nt] = __builtin_amdgcn_mfma_f32_16x16x32_bf16(af, bfr, acc[nt], 0, 0, 0);
            }
        }
#pragma unroll
        for (int nt = 0; nt < 4; nt++) {
            int d = wv * 64 + nt * 16 + lr;
            float bias = W[W_E2B + d];
#pragma unroll
            for (int reg = 0; reg < 4; reg++) {
                int m = quad * 4 + reg;
                float v = acc[nt][reg] + bias;
                v = v > 0.f ? v : 0.01f * v;
                u16 bits = f2bbits(v);
                aeB[m][d] = bits;
                aeb[(r0 + m) * 256 + d] = bits;
            }
        }
    }
    __syncthreads();
    // s1 = ae @ h1w[:,:256].T + h1b ; qk = ae @ M  (M=16, K=256)
    {
        const bf16x8* Bs = (const bf16x8*)(W + W_S1P);
        f32x4 sac[4];
#pragma unroll
        for (int nt = 0; nt < 4; nt++) sac[nt] = (f32x4){0.f, 0.f, 0.f, 0.f};
#pragma unroll
        for (int kt = 0; kt < 8; kt++) {
            bf16x8 af = *(const bf16x8*)&aeB[lr][kt * 32 + (quad << 3)];
#pragma unroll
            for (int nt = 0; nt < 4; nt++) {
                bf16x8 bs = Bs[(kt * 16 + (wv * 4 + nt)) * 64 + ln];
                sac[nt] = __builtin_amdgcn_mfma_f32_16x16x32_bf16(af, bs, sac[nt], 0, 0, 0);
            }
        }
#pragma unroll
        for (int nt = 0; nt < 4; nt++) {
            int d = wv * 64 + nt * 16 + lr;
            float bias = W[W_H1B + d];
#pragma unroll
            for (int reg = 0; reg < 4; reg++) {
                int m = quad * 4 + reg;
                s1ws[(r0 + m) * 256 + d] = sac[nt][reg] + bias;
            }
        }
        if (wv == 0) {
            const bf16x8* Bm = (const bf16x8*)(W + W_QKM);
            f32x4 qk = (f32x4){0.f, 0.f, 0.f, 0.f};
#pragma unroll
            for (int kt = 0; kt < 8; kt++) {
                bf16x8 af = *(const bf16x8*)&aeB[lr][kt * 32 + (quad << 3)];
                qk = __builtin_amdgcn_mfma_f32_16x16x32_bf16(af, Bm[kt * 64 + ln], qk, 0, 0, 0);
            }
            if (lr < 10) {
#pragma unroll
                for (int reg = 0; reg < 4; reg++) {
                    int m = quad * 4 + reg;
                    qkws[(r0 + m) * 10 + lr] = qk[reg];
                }
            }
        }
    }
}

// ---------------- K2: fused edges + hard MLP + gumbel + attention + entropy ----------------
__global__ __launch_bounds__(256) void k_fused(const void* emb, const void* gum,
                                               const float* s1ws, const float* qkws, const float* W,
                                               u16* xb, float* entws, void* out) {
    int flag = detect_flag(emb);
    int r = blockIdx.x;
    int b = r >> 5, i = r & 31;
    __shared__ float embB[32][12];
    __shared__ float seL[32][10];
    __shared__ u16 eA[32][32];
    __shared__ u16 a1[32][264];
    __shared__ float pj[4][32][2];
    __shared__ float cL[32];
    __shared__ float qkL[10];
    int tid = threadIdx.x;
    for (int idx = tid; idx < 32 * 11; idx += 256) {
        int s = idx / 11, t = idx % 11;
        embB[s][t] = ldin(emb, (b * 32 + s) * 11 + t, flag);
    }
    for (int idx = tid; idx < 32 * 32; idx += 256) ((u16*)eA)[idx] = 0;
    if (tid >= 64 && tid < 74) qkL[tid - 64] = qkws[r * 10 + (tid - 64)];
    __syncthreads();
    if (tid < NJ) {
        int jp = tid;
        int j = jp + (jp >= i ? 1 : 0);
        float pix = embB[i][0], piy = embB[i][1], hix = embB[i][2], hiy = embB[i][3];
        float pjx = embB[j][0], pjy = embB[j][1], hjx = embB[j][2], hjy = embB[j][3];
        float ajx = embB[j][7], ajy = embB[j][8];
        float gjx = embB[j][9], gjy = embB[j][10];
        float dx = pjx - pix, dy = pjy - piy;
        float dist = sqrtf(dx * dx + dy * dy);
        float hai = atan2f(hiy, hix);
        float ang = atan2f(dy, dx) - hai;
        float gx = gjx - pix, gy = gjy - piy;
        float gdist = sqrtf(gx * gx + gy * gy);
        float gang = atan2f(gy, gx) - hai;
        float f[10];
        f[0] = dist * (1.f / 12.f);
        f[1] = cosf(ang); f[2] = sinf(ang);
        f[3] = hjx; f[4] = hjy; f[5] = ajx; f[6] = ajy;
        f[7] = gdist; f[8] = cosf(gang); f[9] = sinf(gang);
#pragma unroll
        for (int t = 0; t < 10; t++) seL[jp][t] = f[t];
#pragma unroll
        for (int t = 0; t < 7; t++) eA[jp][t] = f2bbits(f[t]);
        stout(out, OUT2 + r * NJ + jp, dist, flag);
    }
    __syncthreads();
    int wv = tid >> 6, ln = tid & 63;
    int lr = ln & 15, quad = ln >> 4;
    // stage A: a1 = relu(s1 + edge @ W1e^T), s1 folded as C-init
    {
        const bf16x8* Bp = (const bf16x8*)(W + W_W1EP);
        bf16x8 af0 = *(const bf16x8*)&eA[lr][quad << 3];
        bf16x8 af1 = *(const bf16x8*)&eA[16 + lr][quad << 3];
#pragma unroll
        for (int nt = 0; nt < 4; nt++) {
            int gnt = wv * 4 + nt;
            int d = gnt * 16 + lr;
            float s1v = s1ws[r * 256 + d];
            f32x4 acc0 = (f32x4){s1v, s1v, s1v, s1v};
            f32x4 acc1 = acc0;
            bf16x8 bb = Bp[gnt * 64 + ln];
            acc0 = __builtin_amdgcn_mfma_f32_16x16x32_bf16(af0, bb, acc0, 0, 0, 0);
            acc1 = __builtin_amdgcn_mfma_f32_16x16x32_bf16(af1, bb, acc1, 0, 0, 0);
#pragma unroll
            for (int reg = 0; reg < 4; reg++) {
                a1[(quad << 2) + reg][d]      = f2bbits(fmaxf(acc0[reg], 0.f));
                a1[16 + (quad << 2) + reg][d] = f2bbits(fmaxf(acc1[reg], 0.f));
            }
        }
    }
    __syncthreads();
    // stage B: partial logits = a1 @ E^T
    {
        const bf16x8* Ep = (const bf16x8*)(W + W_HE2P);
        f32x4 l0 = (f32x4){0.f, 0.f, 0.f, 0.f};
        f32x4 l1 = (f32x4){0.f, 0.f, 0.f, 0.f};
#pragma unroll
        for (int kk = 0; kk < 2; kk++) {
            int kt = wv * 2 + kk;
            bf16x8 a0 = *(const bf16x8*)&a1[lr][kt * 32 + (quad << 3)];
            bf16x8 a1f = *(const bf16x8*)&a1[16 + lr][kt * 32 + (quad << 3)];
            bf16x8 bb = Ep[kt * 64 + ln];
            l0 = __builtin_amdgcn_mfma_f32_16x16x32_bf16(a0, bb, l0, 0, 0, 0);
            l1 = __builtin_amdgcn_mfma_f32_16x16x32_bf16(a1f, bb, l1, 0, 0, 0);
        }
        if (lr < 2) {
#pragma unroll
            for (int reg = 0; reg < 4; reg++) {
                pj[wv][(quad << 2) + reg][lr]      = l0[reg];
                pj[wv][16 + (quad << 2) + reg][lr] = l1[reg];
            }
        }
    }
    __syncthreads();
    // stage C (wave 0): gumbel + softmax + combined + entropy
    if (wv == 0) {
        float hwv = 0.f;
        if (ln < NJ) {
            float p0 = pj[0][ln][0] + pj[1][ln][0] + pj[2][ln][0] + pj[3][ln][0];
            float p1 = pj[0][ln][1] + pj[1][ln][1] + pj[2][ln][1] + pj[3][ln][1];
            float l0 = p0 + W[W_CB + 0], l1 = p1 + W[W_CB + 1];
            float u0 = ldin(gum, (r * NJ + ln) * 2 + 0, flag);
            float u1 = ldin(gum, (r * NJ + ln) * 2 + 1, flag);
            float g0 = -logf(-logf(u0 + 1e-10f) + 1e-10f);
            float g1 = -logf(-logf(u1 + 1e-10f) + 1e-10f);
            float dl = ((l1 + g1) - (l0 + g0)) * 2.0f;  // / tau (=0.5)
            hwv = 1.f / (1.f + expf(-dl));
            stout(out, OUT1 + r * NJ + ln, l1, flag);
            stout(out, OUT4 + r * NJ + ln, hwv, flag);
        }
        float sc = -1e30f;
        if (ln < NJ) {
            float p = 0.f;
#pragma unroll
            for (int t = 0; t < 10; t++) p += qkL[t] * seL[ln][t];
            sc = p * (1.f / 16.f);
        }
        float m = sc;
#pragma unroll
        for (int s = 32; s >= 1; s >>= 1) m = fmaxf(m, __shfl_xor(m, s, 64));
        float e = (ln < NJ) ? expf(sc - m) : 0.f;
        float sum = e;
#pragma unroll
        for (int s = 32; s >= 1; s >>= 1) sum += __shfl_xor(sum, s, 64);
        float sw = e / sum;
        float cmb = sw * hwv;
        if (ln < NJ) {
            cL[ln] = cmb;
            stout(out, OUT5 + r * NJ + ln, cmb, flag);
        }
        float csum = cmb;
#pragma unroll
        for (int s = 32; s >= 1; s >>= 1) csum += __shfl_xor(csum, s, 64);
        float cwn = cmb / (csum + 1e-6f);
        float et = (ln < NJ) ? -cwn * logf(cwn + 1e-6f) : 0.f;
#pragma unroll
        for (int s = 32; s >= 1; s >>= 1) et += __shfl_xor(et, s, 64);
        if (ln == 0) entws[r] = et;
    }
    __syncthreads();
    // stage D: x = sum_j relu(v_j) * combined_j
    float vwr[10];
#pragma unroll
    for (int t = 0; t < 10; t++) vwr[t] = W[W_VW + tid * 10 + t];
    float vbv = W[W_VB + tid];
    float x = 0.f;
    for (int j = 0; j < NJ; j++) {
        float v = vbv;
#pragma unroll
        for (int t = 0; t < 10; t++) v += vwr[t] * seL[j][t];
        v = fmaxf(v, 0.f);
        x += v * cL[j];
    }
    xb[r * 256 + tid] = f2bbits(x);
}

// ---------------- K3: decoder via MFMA + block-0 entropy epilogue ----------------
__global__ __launch_bounds__(256) void k_dec(const void* emb, const u16* aeb, const u16* xb,
                                             const float* W, const float* entws, void* out) {
    int flag = detect_flag(emb);
    int r0 = (blockIdx.x >> 2) * 32;
    int nq = blockIdx.x & 3;
    __shared__ u16 finB[32][520];
    int tid = threadIdx.x;
    for (int idx = tid; idx < 32 * 512; idx += 256) {
        int s = idx >> 9, c = idx & 511;
        finB[s][c] = (c < 256) ? aeb[(r0 + s) * 256 + c] : xb[(r0 + s) * 256 + (c - 256)];
    }
    __syncthreads();
    int wv = tid >> 6, ln = tid & 63;
    int lr = ln & 15, quad = ln >> 4;
    const bf16x8* Bp = (const bf16x8*)(W + W_DECWT);
    f32x4 acc[2][2];
#pragma unroll
    for (int mt = 0; mt < 2; mt++)
#pragma unroll
        for (int nt = 0; nt < 2; nt++) acc[mt][nt] = (f32x4){0.f, 0.f, 0.f, 0.f};
#pragma unroll
    for (int kt = 0; kt < 16; kt++) {
        bf16x8 af[2];
#pragma unroll
        for (int mt = 0; mt < 2; mt++)
            af[mt] = *(const bf16x8*)&finB[mt * 16 + lr][kt * 32 + (quad << 3)];
#pragma unroll
        for (int nt = 0; nt < 2; nt++) {
            int gnt = nq * 8 + wv * 2 + nt;
            bf16x8 bfr = Bp[(kt * 32 + gnt) * 64 + ln];
#pragma unroll
            for (int mt = 0; mt < 2; mt++)
                acc[mt][nt] = __builtin_amdgcn_mfma_f32_16x16x32_bf16(af[mt], bfr, acc[mt][nt], 0, 0, 0);
        }
    }
#pragma unroll
    for (int nt = 0; nt < 2; nt++) {
        int d = (nq * 8 + wv * 2 + nt) * 16 + lr;
        float bias = W[W_DECB + d];
#pragma unroll
        for (int mt = 0; mt < 2; mt++)
#pragma unroll
            for (int reg = 0; reg < 4; reg++) {
                int m = mt * 16 + quad * 4 + reg;
                stout(out, OUT0 + (r0 + m) * 512 + d, acc[mt][nt][reg] + bias, flag);
            }
    }
    // entropy mean epilogue on block 0 (entws is complete before this kernel starts)
    if (blockIdx.x == 0) {
        __shared__ float red[4];
        float s = 0.f;
        for (int i2 = tid; i2 < R_TOT; i2 += 256) s += entws[i2];
#pragma unroll
        for (int m = 32; m >= 1; m >>= 1) s += __shfl_xor(s, m, 64);
        if ((tid & 63) == 0) red[tid >> 6] = s;
        __syncthreads();
        if (tid == 0) {
            float t = red[0] + red[1] + red[2] + red[3];
            stout(out, OUT3, t / (float)R_TOT, flag);
        }
    }
}

// ---------------- launch ----------------
extern "C" void kernel_launch(void* const* d_in, const int* in_sizes, int n_in,
                              void* d_out, int out_size, void* d_ws, size_t ws_size,
                              hipStream_t stream) {
    const void* emb  = d_in[0];
    const void* gum  = d_in[1];
    const void* e1w  = d_in[2];
    const void* e1b  = d_in[3];
    const void* e2w  = d_in[4];
    const void* e2b  = d_in[5];
    const void* h1w  = d_in[6];
    const void* h1b  = d_in[7];
    const void* h2w  = d_in[8];
    const void* h2b  = d_in[9];
    const void* hew  = d_in[10];
    const void* heb  = d_in[11];
    const void* qw   = d_in[12];
    const void* kw   = d_in[13];
    const void* vw   = d_in[14];
    const void* vb   = d_in[15];
    const void* decw = d_in[16];
    const void* decb = d_in[17];

    float* wsf = (float*)d_ws;
    u16*   aeb  = (u16*)(wsf + OFF_AE);
    float* qkws = wsf + OFF_QK;
    float* s1ws = wsf + OFF_S1;
    float* entw = wsf + OFF_ENT;
    u16*   xb   = (u16*)(wsf + OFF_X);
    float* W    = wsf + OFF_W;

    hipLaunchKernelGGL(k_prep, dim3(2593), dim3(256), 0, stream,
                       emb, e1w, e1b, e2w, e2b, h1w, h1b, h2w, h2b, hew, heb,
                       qw, kw, vw, vb, decw, decb, W);
    hipLaunchKernelGGL(k_embed, dim3(256), dim3(256), 0, stream, emb, W, aeb, qkws, s1ws);
    hipLaunchKernelGGL(k_fused, dim3(4096), dim3(256), 0, stream,
                       emb, gum, s1ws, qkws, W, xb, entw, d_out);
    hipLaunchKernelGGL(k_dec, dim3(512), dim3(256), 0, stream, emb, aeb, xb, W, entw, d_out);
}